// Round 1
// baseline (274.289 us; speedup 1.0000x reference)
//
#include <hip/hip_runtime.h>
#include <hip/hip_bf16.h>

#define B_ 4
#define M_ 1024
#define ND_ 64
#define ED_ 8
#define D_ 64
#define H_ 4
#define KT 16          // k-rows per block
#define QC 64          // q-chunk
#define NCH (M_ / QC)  // 16 chunks
#define ALPHA 0.2f

// ---------------- ws layout (floats) ----------------
// Wh  : [B][H][M][D]  = 1048576
// Wh1 : [B][H][M]     = 16384
// Wh2 : [B][H][M]     = 16384
// w_e : [H][ED]       = 32
#define WS_WH1 1048576
#define WS_WH2 1064960
#define WS_WE  1081344

__device__ __forceinline__ float4 f4fma(float s, const float4& v, float4 a) {
    a.x = fmaf(s, v.x, a.x);
    a.y = fmaf(s, v.y, a.y);
    a.z = fmaf(s, v.z, a.z);
    a.w = fmaf(s, v.w, a.w);
    return a;
}

// ---------------- kernel 1: Wh, Wh1, Wh2 ----------------
// grid 4096 x 256. thread -> (b,h,m,d); wave = one (b,h,m) row (64 d lanes).
__global__ __launch_bounds__(256) void k_pre(const float* __restrict__ hg,
                                             const float* __restrict__ Wg,
                                             const float* __restrict__ ag,
                                             float* __restrict__ Whg,
                                             float* __restrict__ Wh1g,
                                             float* __restrict__ Wh2g) {
    const int t = threadIdx.x;
    const int g = blockIdx.x * 256 + t;
    const int d = t & 63;
    const int bhm = g >> 6;
    const int m = bhm & (M_ - 1);
    const int h = (bhm >> 10) & (H_ - 1);
    const int b = bhm >> 12;
    const float* hrow = hg + (b * M_ + m) * ND_;
    const float* wcol = Wg + h * ND_ * D_ + d;
    float acc = 0.f;
#pragma unroll
    for (int i = 0; i < ND_; ++i) acc = fmaf(hrow[i], wcol[i * D_], acc);
    Whg[g] = acc;
    // fused Wh1/Wh2 wave reductions
    float r1 = acc * ag[h * 192 + d];
    float r2 = acc * ag[h * 192 + 64 + d];
#pragma unroll
    for (int off = 32; off >= 1; off >>= 1) {
        r1 += __shfl_xor(r1, off);
        r2 += __shfl_xor(r2, off);
    }
    if (d == 0) {
        Wh1g[(b * H_ + h) * M_ + m] = r1;
        Wh2g[(b * H_ + h) * M_ + m] = r2;
    }
}

// ---------------- kernel 2: w_e ----------------
__global__ void k_we(const float* __restrict__ Weg, const float* __restrict__ ag,
                     float* __restrict__ weg) {
    const int t = threadIdx.x;
    if (t < H_ * ED_) {
        const int h = t >> 3, e = t & 7;
        const float* wrow = Weg + (h * ED_ + e) * D_;
        const float* a3 = ag + h * 192 + 128;
        float acc = 0.f;
#pragma unroll
        for (int i = 0; i < D_; ++i) acc = fmaf(wrow[i], a3[i], acc);
        weg[t] = acc;
    }
}

// ---------------- kernel 3: fused e -> softmax -> PV ----------------
// grid 256 x 1024. block = (b, 16 k-rows). 16 waves.
// e-mapping : wave wv owns k-row (k0+wv), lane = q within chunk.
// PV-mapping: wave = (kq = wv>>2 owning 4 k's, qg = wv&3 owning 16 q's);
//             lane = (h = lane>>4, d4 = lane&15) -> 4 floats of d.
// LDS (dynamic, 82432 B):
//   whl [QC][H*D]              16384 f  (row q = 1KB, lane*16B layout; also reused
//                                        as the qg-partial reduction buffer at end)
//   pb  [H][KT*QC + 8]          4128 f  (h-plane pad 8 -> bank offset 8h)
//   wel [32], sl [64]
__global__ __launch_bounds__(1024) void k_main(const float* __restrict__ cvg,
                                               const int* __restrict__ mg,
                                               const float* __restrict__ Whg,
                                               const float* __restrict__ Wh1g,
                                               const float* __restrict__ Wh2g,
                                               const float* __restrict__ weg,
                                               float* __restrict__ outg) {
    extern __shared__ float smem[];
    float* whl = smem;            // 16384
    float* pb = smem + 16384;     // 4128
    float* wel = smem + 20512;    // 32
    float* sl = smem + 20544;     // 64
    float4* wh4 = (float4*)whl;
    float4* pb4 = (float4*)pb;
    const float4* we4 = (const float4*)wel;

    const int t = threadIdx.x;
    const int lane = t & 63, wv = t >> 6;
    const int b = blockIdx.x >> 6;
    const int k0 = (blockIdx.x & 63) << 4;
    const int hh = lane >> 4, d4 = lane & 15;

    if (t < 32) wel[t] = weg[t];

    const int ek = k0 + wv;  // e-phase row for this wave
    float wh1r[H_];
#pragma unroll
    for (int h = 0; h < H_; ++h) wh1r[h] = Wh1g[(b * H_ + h) * M_ + ek];

    float4 acc[4];
#pragma unroll
    for (int i = 0; i < 4; ++i) acc[i] = make_float4(0.f, 0.f, 0.f, 0.f);
    float sreg[H_] = {0.f, 0.f, 0.f, 0.f};

    const float4* cvrow = (const float4*)(cvg + (size_t)(b * M_ + ek) * M_ * ED_);
    const int* mrow = mg + (size_t)(b * M_ + ek) * M_;

    // stage Wh chunk 0 into LDS (async, drained by the barrier)
#pragma unroll
    for (int i = 0; i < 4; ++i) {
        const int ql = wv * 4 + i;
        const float* src = Whg + ((size_t)((b * H_ + hh) * M_) + ql) * D_ + d4 * 4;
        __builtin_amdgcn_global_load_lds((const __attribute__((address_space(1))) void*)src,
                                         (__attribute__((address_space(3))) void*)(whl + ql * 256),
                                         16, 0, 0);
    }
    // prefetch chunk-0 inputs into registers
    float4 cv0 = cvrow[lane * 2 + 0];
    float4 cv1 = cvrow[lane * 2 + 1];
    int mk = mrow[lane];
    float wh2r[H_];
#pragma unroll
    for (int h = 0; h < H_; ++h) wh2r[h] = Wh2g[(b * H_ + h) * M_ + lane];

    __syncthreads();

    for (int c = 0; c < NCH; ++c) {
        // ---- e-phase: e = Wh1 + Wh2 + cv.w_e ; leaky-relu ; mask ; p = exp(e) ----
        float pv[H_];
#pragma unroll
        for (int h = 0; h < H_; ++h) {
            const float4 wa = we4[h * 2], wb = we4[h * 2 + 1];
            float ef = cv0.x * wa.x + cv0.y * wa.y + cv0.z * wa.z + cv0.w * wa.w +
                       cv1.x * wb.x + cv1.y * wb.y + cv1.z * wb.z + cv1.w * wb.w;
            float e = wh1r[h] + wh2r[h] + ef;
            e = fmaxf(e, ALPHA * e);                   // leaky relu (ALPHA < 1)
            pv[h] = (mk > 0) ? __expf(e) : 0.0f;       // masked -> exp(NEG) == 0
            pb[h * 1032 + wv * QC + lane] = pv[h];
        }
        // running softmax denominator (butterfly; identical in all lanes)
#pragma unroll
        for (int h = 0; h < H_; ++h) {
            float r = pv[h];
#pragma unroll
            for (int off = 32; off >= 1; off >>= 1) r += __shfl_xor(r, off);
            sreg[h] += r;
        }
        __syncthreads();  // p ready; Wh chunk c guaranteed staged (vmcnt drain)

        // ---- prefetch chunk c+1 inputs (in flight across PV) ----
        if (c + 1 < NCH) {
            const int qn = (c + 1) * QC + lane;
            cv0 = cvrow[qn * 2 + 0];
            cv1 = cvrow[qn * 2 + 1];
            mk = mrow[qn];
#pragma unroll
            for (int h = 0; h < H_; ++h) wh2r[h] = Wh2g[(b * H_ + h) * M_ + qn];
        }

        // ---- PV: acc[k] += p[h][k][q] * Wh[q][h][d] ----
        {
            const int kq = wv >> 2, qg = wv & 3;
#pragma unroll
            for (int j = 0; j < 4; ++j) {
                const int ql = qg * 16 + j * 4;
                const float4 w0 = wh4[(ql + 0) * 64 + lane];
                const float4 w1 = wh4[(ql + 1) * 64 + lane];
                const float4 w2 = wh4[(ql + 2) * 64 + lane];
                const float4 w3 = wh4[(ql + 3) * 64 + lane];
#pragma unroll
                for (int kk = 0; kk < 4; ++kk) {
                    const float4 pq = pb4[hh * 258 + (kq * 4 + kk) * 16 + (ql >> 2)];
                    float4 a = acc[kk];
                    a = f4fma(pq.x, w0, a);
                    a = f4fma(pq.y, w1, a);
                    a = f4fma(pq.z, w2, a);
                    a = f4fma(pq.w, w3, a);
                    acc[kk] = a;
                }
            }
        }
        __syncthreads();  // Wh chunk consumed -> safe to overwrite

        // ---- stage Wh chunk c+1 (overlaps next e-phase) ----
        if (c + 1 < NCH) {
#pragma unroll
            for (int i = 0; i < 4; ++i) {
                const int ql = wv * 4 + i;
                const float* src =
                    Whg + ((size_t)((b * H_ + hh) * M_) + (c + 1) * QC + ql) * D_ + d4 * 4;
                __builtin_amdgcn_global_load_lds(
                    (const __attribute__((address_space(1))) void*)src,
                    (__attribute__((address_space(3))) void*)(whl + ql * 256), 16, 0, 0);
            }
        }
    }

    // ---- epilogue: combine qg partials, scale by 1/s, write ----
    if (lane == 0) {
#pragma unroll
        for (int h = 0; h < H_; ++h) sl[wv * H_ + h] = sreg[h];
    }
    __syncthreads();
    {
        const int kq = wv >> 2, qg = wv & 3;
#pragma unroll
        for (int kk = 0; kk < 4; ++kk)
            wh4[((kq * 4 + kk) * 4 + qg) * 64 + lane] = acc[kk];
    }
    __syncthreads();
    {
        const float4 r0 = wh4[(wv * 4 + 0) * 64 + lane];
        const float4 r1 = wh4[(wv * 4 + 1) * 64 + lane];
        const float4 r2 = wh4[(wv * 4 + 2) * 64 + lane];
        const float4 r3 = wh4[(wv * 4 + 3) * 64 + lane];
        const float inv = 1.0f / sl[wv * H_ + hh];
        float4 r;
        r.x = (r0.x + r1.x + r2.x + r3.x) * inv;
        r.y = (r0.y + r1.y + r2.y + r3.y) * inv;
        r.z = (r0.z + r1.z + r2.z + r3.z) * inv;
        r.w = (r0.w + r1.w + r2.w + r3.w) * inv;
        float4* o4 = (float4*)(outg + (size_t)(b * M_ + k0 + wv) * (H_ * D_));
        o4[lane] = r;
    }
}

extern "C" void kernel_launch(void* const* d_in, const int* in_sizes, int n_in,
                              void* d_out, int out_size, void* d_ws, size_t ws_size,
                              hipStream_t stream) {
    const float* hg = (const float*)d_in[0];
    const int* mg = (const int*)d_in[1];
    const float* cvg = (const float*)d_in[2];
    const float* Wg = (const float*)d_in[3];
    const float* Weg = (const float*)d_in[4];
    const float* ag = (const float*)d_in[5];
    float* outg = (float*)d_out;
    float* ws = (float*)d_ws;
    float* Whg = ws;
    float* Wh1g = ws + WS_WH1;
    float* Wh2g = ws + WS_WH2;
    float* weg = ws + WS_WE;

    // 82 KB dynamic LDS (> 64 KB static limit); idempotent, capture-safe host call
    (void)hipFuncSetAttribute((const void*)k_main,
                              hipFuncAttributeMaxDynamicSharedMemorySize, 82432);

    k_pre<<<4096, 256, 0, stream>>>(hg, Wg, ag, Whg, Wh1g, Wh2g);
    k_we<<<1, 64, 0, stream>>>(Weg, ag, weg);
    k_main<<<256, 1024, 82432, stream>>>(cvg, mg, Whg, Wh1g, Wh2g, weg, outg);
}